// Round 16
// baseline (276.322 us; speedup 1.0000x reference)
//
#include <hip/hip_runtime.h>

// B=4, T=1024, C=512, H=8, HD=64, NE=8, K(topk)=2, FF=2048
// Round-16: G1 moved to gemm1s — BM=256 x BN=64, 4 M-stacked waves,
// 64 acc-VGPR, 40KB single-buffered LDS -> 3-4 blocks/CU (cross-block
// overlap, the only untested occupancy quadrant). G2/combine/attention
// unchanged from r15 best (269.2us).

typedef unsigned short u16;
typedef __attribute__((ext_vector_type(8))) short s16x8;
typedef __attribute__((ext_vector_type(4))) float f32x4;

__device__ __forceinline__ u16 f2bf(float f) {
  union { float f; unsigned u; } v; v.f = f;
  unsigned r = v.u + 0x7fffu + ((v.u >> 16) & 1u);  // RNE
  return (u16)(r >> 16);
}
__device__ __forceinline__ float bf2f(u16 h) {
  union { unsigned u; float f; } v; v.u = ((unsigned)h) << 16;
  return v.f;
}

#define GLDS16(g, s) __builtin_amdgcn_global_load_lds( \
    (const __attribute__((address_space(1))) void*)(g), \
    (__attribute__((address_space(3))) void*)(s), 16, 0, 0)

#define MFMA16(a, b, c) __builtin_amdgcn_mfma_f32_16x16x32_bf16((a), (b), (c), 0, 0, 0)

// -------- transpose + fp32->bf16 convert: in [R][C] fp32 -> out [C][R] bf16 --
__global__ __launch_bounds__(256) void transpose_k(
    const float* __restrict__ in, u16* __restrict__ out,
    int R, int C, long long ibs, long long obs, float scale)
{
  __shared__ float tile[32][33];
  in  += (long long)blockIdx.z * ibs;
  out += (long long)blockIdx.z * obs;
  const int c0 = blockIdx.x * 32, r0 = blockIdx.y * 32;
  const int tx = threadIdx.x, ty = threadIdx.y;  // (32,8)
  #pragma unroll
  for (int i = 0; i < 4; ++i)
    tile[ty + i*8][tx] = in[(size_t)(r0 + ty + i*8) * C + c0 + tx];
  __syncthreads();
  #pragma unroll
  for (int i = 0; i < 4; ++i)
    out[(size_t)(c0 + ty + i*8) * R + r0 + tx] = f2bf(tile[tx][ty + i*8] * scale);
}

// -------- merged W1+W2 prep: z<8 = W1 e=z; z>=8 = W2 e=z-8 -> flat [512][16384]
__global__ __launch_bounds__(256) void transW_k(
    const float* __restrict__ W1, const float* __restrict__ W2,
    u16* __restrict__ w1t, u16* __restrict__ w2f)
{
  __shared__ float tile[32][33];
  const int z = blockIdx.z;
  const int tx = threadIdx.x, ty = threadIdx.y;
  if (z < 8) {
    const float* in = W1 + (size_t)z * 512 * 2048;
    u16* out = w1t + (size_t)z * 2048 * 512;
    const int c0 = blockIdx.x * 32, r0 = blockIdx.y * 32;
    #pragma unroll
    for (int i = 0; i < 4; ++i)
      tile[ty + i*8][tx] = in[(size_t)(r0 + ty + i*8) * 2048 + c0 + tx];
    __syncthreads();
    #pragma unroll
    for (int i = 0; i < 4; ++i)
      out[(size_t)(c0 + ty + i*8) * 512 + r0 + tx] = f2bf(tile[tx][ty + i*8]);
  } else {
    const int e = z - 8;
    const float* in = W2 + (size_t)e * 2048 * 512;
    const int r0 = blockIdx.x * 32, c0 = blockIdx.y * 32;
    #pragma unroll
    for (int i = 0; i < 4; ++i)
      tile[ty + i*8][tx] = in[(size_t)(r0 + ty + i*8) * 512 + c0 + tx];
    __syncthreads();
    #pragma unroll
    for (int i = 0; i < 4; ++i)
      w2f[(size_t)(c0 + ty + i*8) * 16384 + e*2048 + r0 + tx] = f2bf(tile[tx][ty + i*8]);
  }
}

// -------- merged Wq/Wk/Wv (+Wp) transpose --------------------------------------
__global__ __launch_bounds__(256) void transqkv_k(
    const float* __restrict__ Wq, const float* __restrict__ Wk,
    const float* __restrict__ Wv, const float* __restrict__ Wp,
    u16* __restrict__ oqkv, u16* __restrict__ owp)
{
  __shared__ float tile[32][33];
  const int z = blockIdx.z;
  const int tx = threadIdx.x, ty = threadIdx.y;
  if (z < 24) {
    const int which = z >> 3, head = z & 7;
    const float* in = (which == 0 ? Wq : (which == 1 ? Wk : Wv)) + (size_t)head * 512 * 64;
    u16* o = oqkv + (size_t)which * 512 * 512 + (size_t)head * 64 * 512;
    const float scale = (which == 0) ? 0.125f : 1.f;
    const int c0 = blockIdx.x * 32, r0 = blockIdx.y * 32;
    #pragma unroll
    for (int i = 0; i < 4; ++i)
      tile[ty + i*8][tx] = in[(size_t)(r0 + ty + i*8) * 64 + c0 + tx];
    __syncthreads();
    #pragma unroll
    for (int i = 0; i < 4; ++i)
      o[(size_t)(c0 + ty + i*8) * 512 + r0 + tx] = f2bf(tile[tx][ty + i*8] * scale);
  } else {
    const int zz = z - 24;
    const int c0 = (zz * 2 + blockIdx.x) * 32;
    const int r0 = blockIdx.y * 32;
    #pragma unroll
    for (int i = 0; i < 4; ++i)
      tile[ty + i*8][tx] = Wp[(size_t)(r0 + ty + i*8) * 512 + c0 + tx];
    __syncthreads();
    #pragma unroll
    for (int i = 0; i < 4; ++i)
      owp[(size_t)(c0 + ty + i*8) * 512 + r0 + tx] = f2bf(tile[tx][ty + i*8]);
  }
}

// -------- V transpose: qkv V-section -> vt[bh][64 d][1024 t] bf16 ------------
__global__ __launch_bounds__(256) void vtrans_k(
    const u16* __restrict__ qkv, u16* __restrict__ vt)
{
  __shared__ u16 tile[32][33];
  const int bh = blockIdx.z, b = bh >> 3, h = bh & 7;
  const int t0 = blockIdx.x * 32, d0 = blockIdx.y * 32;
  const int tx = threadIdx.x, ty = threadIdx.y;
  #pragma unroll
  for (int i = 0; i < 4; ++i)
    tile[ty + i*8][tx] = qkv[(size_t)(b*1024 + t0 + ty + i*8) * 1536 + 1024 + h*64 + d0 + tx];
  __syncthreads();
  #pragma unroll
  for (int i = 0; i < 4; ++i)
    vt[(size_t)bh*65536 + (size_t)(d0 + ty + i*8) * 1024 + t0 + tx] = tile[tx][ty + i*8];
}

// -------- LayerNorm (C=512): fp32 in -> bf16 out -----------------------------
__global__ __launch_bounds__(256) void ln_k(
    const float* __restrict__ x, const float* __restrict__ g,
    const float* __restrict__ b, u16* __restrict__ o)
{
  const int row = blockIdx.x, t = threadIdx.x;
  const float* xr = x + (size_t)row * 512;
  const float a0 = xr[t], a1 = xr[t + 256];
  float s = a0 + a1, ss = a0*a0 + a1*a1;
  #pragma unroll
  for (int off = 1; off < 64; off <<= 1) {
    s  += __shfl_xor(s, off);
    ss += __shfl_xor(ss, off);
  }
  __shared__ float rs[4], rq[4];
  const int w = t >> 6;
  if ((t & 63) == 0) { rs[w] = s; rq[w] = ss; }
  __syncthreads();
  s  = rs[0] + rs[1] + rs[2] + rs[3];
  ss = rq[0] + rq[1] + rq[2] + rq[3];
  const float mu = s * (1.f/512.f);
  const float var = ss * (1.f/512.f) - mu*mu;
  const float rstd = rsqrtf(var + 1e-5f);
  o[(size_t)row*512 + t]       = f2bf((a0 - mu) * rstd * g[t]     + b[t]);
  o[(size_t)row*512 + t + 256] = f2bf((a1 - mu) * rstd * g[t+256] + b[t+256]);
}

// -------- gemm1s: BM=256 x BN=64, 4 M-stacked waves, single-buffer 40KB LDS --
// 3-4 blocks/CU cross-block overlap. G1-half: gate+relu write N=16384,
// XCD col-ownership (bid&7 owns cols [r*2048,(r+1)*2048)).
__global__ __launch_bounds__(256) void gemm1s(
    const u16* __restrict__ A, const u16* __restrict__ Bt,
    u16* __restrict__ obf, const float* __restrict__ bias,
    const float* __restrict__ rout)
{
  __shared__ u16 Asm[256*64];   // 32 KB
  __shared__ u16 Bsm[64*64];    // 8 KB
  const int t = threadIdx.x, l = t & 63, wid = t >> 6;
  const int lrow = l & 15, lhi = l >> 4;

  const int r8 = blockIdx.x & 7, j = blockIdx.x >> 3;   // 2048 blocks
  const int n0 = r8 * 2048 + (j & 31) * 64;
  const int m0 = (j >> 5) * 256;

  const f32x4 z4 = {0.f, 0.f, 0.f, 0.f};
  f32x4 acc[4][4];
  #pragma unroll
  for (int i = 0; i < 4; ++i)
    #pragma unroll
    for (int jj = 0; jj < 4; ++jj) acc[i][jj] = z4;

  const int tr = t >> 3;
  const int csw = ((t & 7) ^ (tr & 7)) * 8;
  const u16* ga = A  + (size_t)(m0 + tr) * 512 + csw;
  const u16* gb = Bt + (size_t)(n0 + tr) * 512 + csw;

#define RD1(Ls, row, kb) (*(const s16x8*)((const char*)(Ls) + (row)*128 + ((kb) ^ (((row)&7)<<4))))

  for (int k0 = 0; k0 < 512; k0 += 64) {
    #pragma unroll
    for (int i = 0; i < 8; ++i)
      GLDS16(ga + (size_t)(i*32)*512 + k0, (char*)Asm + i*4096 + t*16);
    #pragma unroll
    for (int i = 0; i < 2; ++i)
      GLDS16(gb + (size_t)(i*32)*512 + k0, (char*)Bsm + i*4096 + t*16);
    asm volatile("s_waitcnt vmcnt(0)" ::: "memory");
    __builtin_amdgcn_sched_barrier(0);
    __builtin_amdgcn_s_barrier();
    #pragma unroll
    for (int kh = 0; kh < 2; ++kh) {
      s16x8 af[4], bfr[4];
      #pragma unroll
      for (int i = 0; i < 4; ++i)
        af[i]  = RD1(Asm, wid*64 + i*16 + lrow, kh*64 + lhi*16);
      #pragma unroll
      for (int jj = 0; jj < 4; ++jj)
        bfr[jj] = RD1(Bsm, jj*16 + lrow, kh*64 + lhi*16);
      #pragma unroll
      for (int i = 0; i < 4; ++i)
        #pragma unroll
        for (int jj = 0; jj < 4; ++jj)
          acc[i][jj] = MFMA16(af[i], bfr[jj], acc[i][jj]);
    }
    __builtin_amdgcn_s_barrier();
    __builtin_amdgcn_sched_barrier(0);
  }
#undef RD1

  #pragma unroll
  for (int i = 0; i < 4; ++i) {
    const int rbase = m0 + wid*64 + i*16 + lhi*4;
    #pragma unroll
    for (int jj = 0; jj < 4; ++jj) {
      const int col = n0 + jj*16 + lrow;
      #pragma unroll
      for (int rr = 0; rr < 4; ++rr) {
        const int row = rbase + rr;
        const float r = rout[(size_t)row*8 + (col >> 11)];
        obf[(size_t)row*16384 + col] =
            f2bf(fmaxf(acc[i][jj][rr] + bias[col], 0.f) * r);
      }
    }
  }
}

// -------- gemm2p: 128xBN BK=64, 4 waves, dbuf, counted vmcnt, LDS swizzle ----
template<int BN, int EPI>
__global__ __launch_bounds__(256) void gemm2p(
    const u16* __restrict__ A, const u16* __restrict__ Bt,
    int M, int N, int K, int lda, int ldb,
    u16* __restrict__ obf, float* __restrict__ oa,
    const float* __restrict__ bias, const float* __restrict__ extra, int e0)
{
  constexpr int NB = BN / 32;
  constexpr int SB = BN / 32;
  __shared__ u16 Asm[2][128*64];
  __shared__ u16 Bsm[2][BN*64];
  const int t = threadIdx.x, l = t & 63;
  const int wid = t >> 6, wr = wid >> 1, wc = wid & 1;
  const int lrow = l & 15, lhi = l >> 4;
  const int m0 = blockIdx.x * 128, n0 = blockIdx.y * BN;

  const f32x4 z4 = {0.f, 0.f, 0.f, 0.f};
  f32x4 acc[4][NB];
  #pragma unroll
  for (int i = 0; i < 4; ++i)
    #pragma unroll
    for (int j = 0; j < NB; ++j) acc[i][j] = z4;

  const int csw = ((t & 7) ^ ((t >> 3) & 7)) * 8;
  const u16* ga = A  + (size_t)(m0 + (t >> 3)) * lda + csw;
  const u16* gb = Bt + (size_t)(n0 + (t >> 3)) * ldb + csw;

#define STG2(buf, k0) do { \
    _Pragma("unroll") \
    for (int i = 0; i < 4; ++i) \
      GLDS16(ga + (size_t)(i*32)*lda + (k0), (char*)Asm[buf] + i*4096 + t*16); \
    _Pragma("unroll") \
    for (int i = 0; i < SB; ++i) \
      GLDS16(gb + (size_t)(i*32)*ldb + (k0), (char*)Bsm[buf] + i*4096 + t*16); \
  } while (0)

#define RD2(Ls, row, kb) (*(const s16x8*)((const char*)(Ls) + (row)*128 + ((kb) ^ (((row)&7)<<4))))

  const int NT = K >> 6;
  STG2(0, 0);
  for (int tt = 0; tt < NT; ++tt) {
    if (tt + 1 < NT) {
      STG2((tt + 1) & 1, (tt + 1) * 64);
      if constexpr (BN == 128)     asm volatile("s_waitcnt vmcnt(8)" ::: "memory");
      else if constexpr (BN == 96) asm volatile("s_waitcnt vmcnt(7)" ::: "memory");
      else                         asm volatile("s_waitcnt vmcnt(6)" ::: "memory");
    } else {
      asm volatile("s_waitcnt vmcnt(0)" ::: "memory");
    }
    __builtin_amdgcn_sched_barrier(0);
    __builtin_amdgcn_s_barrier();
    const u16* As = Asm[tt & 1];
    const u16* Bs = Bsm[tt & 1];
    #pragma unroll
    for (int kh = 0; kh < 2; ++kh) {
      s16x8 af[4], bfr[NB];
      #pragma unroll
      for (int i = 0; i < 4; ++i)
        af[i]  = RD2(As, wr*64 + i*16 + lrow, kh*64 + lhi*16);
      #pragma unroll
      for (int j = 0; j < NB; ++j)
        bfr[j] = RD2(Bs, wc*(BN/2) + j*16 + lrow, kh*64 + lhi*16);
      #pragma unroll
      for (int i = 0; i < 4; ++i)
        #pragma unroll
        for (int j = 0; j < NB; ++j)
          acc[i][j] = MFMA16(af[i], bfr[j], acc[i][j]);
    }
    __builtin_amdgcn_s_barrier();
    __builtin_amdgcn_sched_barrier(0);
  }
#undef STG2
#undef RD2

  #pragma unroll
  for (int i = 0; i < 4; ++i) {
    const int rbase = m0 + wr*64 + i*16 + lhi*4;
    #pragma unroll
    for (int j = 0; j < NB; ++j) {
      const int col = n0 + wc*(BN/2) + j*16 + lrow;
      #pragma unroll
      for (int rr = 0; rr < 4; ++rr) {
        const int row = rbase + rr;
        const float v = acc[i][j][rr];
        if (EPI == 0) {
          obf[(size_t)row*N + col] = f2bf(v);
        } else if (EPI == 1) {
          const float r = extra[(size_t)row*8 + e0 + (col >> 11)];
          obf[(size_t)row*N + col] = f2bf(fmaxf(v + bias[col], 0.f) * r);
        } else {
          oa[(size_t)row*N + col] = v + bias[col] + extra[(size_t)row*N + col];
        }
      }
    }
  }
}

// -------- gemm8p: 256x256, 8 waves (2x4), BK=64, 2-phase/K-tile (r12 best) ---
template<int NKT, int EPI>
__global__ __launch_bounds__(512, 2) void gemm8p(
    const u16* __restrict__ A, const u16* __restrict__ Bt,
    int lda, int ldb,
    u16* __restrict__ obf,
    const float* __restrict__ bias, const float* __restrict__ rout)
{
  __shared__ u16 Lds[2][2][256*64];   // 128 KiB
  const int t = threadIdx.x, l = t & 63;
  const int wid = t >> 6, wm = wid >> 2, wn = wid & 3;
  const int lrow = l & 15, lhi = l >> 4;

  int m0, n0, zz = 0;
  {
    const int bid = blockIdx.x;
    const int r = bid & 7, k = bid >> 3;
    if (EPI == 1) {
      m0 = (k >> 3) * 256; n0 = (r * 8 + (k & 7)) * 256;
    } else if (EPI == 2) {
      n0 = (r * 8 + (k & 7)) * 256; m0 = (k >> 3) * 256;
    } else if (EPI == 4) {
      zz = r*4 + (k & 3);
      const int mn = k >> 2;
      m0 = (mn >> 1) * 256; n0 = (mn & 1) * 256;
    } else {
      zz = r*2 + (k & 1);
      const int mn = k >> 1;
      m0 = (mn >> 1) * 256; n0 = (mn & 1) * 256;
    }
  }
  constexpr int KCH = (EPI == 4) ? 512 : 1024;
  const u16* Ab = A  + (size_t)m0 * lda + ((EPI == 4 || EPI == 5) ? zz * KCH : 0);
  const u16* Bb = Bt + (size_t)n0 * ldb + ((EPI == 4 || EPI == 5) ? zz * KCH : 0);

  const int tr = t >> 3;
  const int sc = ((t & 7) ^ (tr & 7)) * 8;

#define STGU(bf, kt, op_, u4_) do { \
    const u16* s_ = (op_) ? Bb : Ab; \
    const int ld_ = (op_) ? ldb : lda; \
    GLDS16(s_ + (size_t)((u4_)*64 + tr) * ld_ + (size_t)(kt)*64 + sc, \
           (char*)&Lds[bf][op_][0] + (u4_)*8192 + t*16); \
  } while (0)

#define RD(Ls, row, kb) (*(const s16x8*)((const char*)(Ls) + (row)*128 + ((kb) ^ (((row)&7)<<4))))

  f32x4 acc[8][4];
  const f32x4 z4 = {0.f, 0.f, 0.f, 0.f};
  #pragma unroll
  for (int i = 0; i < 8; ++i)
    #pragma unroll
    for (int j = 0; j < 4; ++j) acc[i][j] = z4;

  #pragma unroll
  for (int u = 0; u < 4; ++u) STGU(0, 0, 0, u);
  #pragma unroll
  for (int u = 0; u < 4; ++u) STGU(0, 0, 1, u);
  if (NKT > 1) {
    #pragma unroll
    for (int u = 0; u < 4; ++u) STGU(1, 1, 1, u);
    asm volatile("s_waitcnt vmcnt(4)" ::: "memory");
  } else {
    asm volatile("s_waitcnt vmcnt(0)" ::: "memory");
  }
  __builtin_amdgcn_sched_barrier(0);
  __builtin_amdgcn_s_barrier();

  s16x8 frA[2][4], frB[2][4];
  #pragma unroll 2
  for (int X = 0; X < NKT; ++X) {
    const u16* As = &Lds[X & 1][0][0];
    const u16* Bs = &Lds[X & 1][1][0];
    // ---- phase 0 ----
    #pragma unroll
    for (int kk = 0; kk < 2; ++kk) {
      #pragma unroll
      for (int nf = 0; nf < 4; ++nf)
        frB[kk][nf] = RD(Bs, wn*64 + nf*16 + lrow, kk*64 + lhi*16);
      #pragma unroll
      for (int mf = 0; mf < 4; ++mf)
        frA[kk][mf] = RD(As, wm*128 + mf*16 + lrow, kk*64 + lhi*16);
    }
    if (X + 1 < NKT) {
      #pragma unroll
      for (int u = 0; u < 4; ++u) STGU((X + 1) & 1, X + 1, 0, u);
    }
    __builtin_amdgcn_s_barrier();
    asm volatile("s_waitcnt lgkmcnt(0)" ::: "memory");
    __builtin_amdgcn_sched_barrier(0);
    __builtin_amdgcn_s_setprio(1);
    #pragma unroll
    for (int kk = 0; kk < 2; ++kk)
      #pragma unroll
      for (int mf = 0; mf < 4; ++mf)
        #pragma unroll
        for (int nf = 0; nf < 4; ++nf)
          acc[mf][nf] = MFMA16(frA[kk][mf], frB[kk][nf], acc[mf][nf]);
    __builtin_amdgcn_s_setprio(0);
    __builtin_amdgcn_s_barrier();
    // ---- phase 1 ----
    #pragma unroll
    for (int kk = 0; kk < 2; ++kk)
      #pragma unroll
      for (int mf = 0; mf < 4; ++mf)
        frA[kk][mf] = RD(As, wm*128 + 64 + mf*16 + lrow, kk*64 + lhi*16);
    if (X + 2 < NKT) {
      #pragma unroll
      for (int u = 0; u < 4; ++u) STGU(X & 1, X + 2, 1, u);
    }
    __builtin_amdgcn_s_barrier();
    asm volatile("s_waitcnt lgkmcnt(0)" ::: "memory");
    __builtin_amdgcn_sched_barrier(0);
    __builtin_amdgcn_s_setprio(1);
    #pragma unroll
    for (int kk = 0; kk < 2; ++kk)
      #pragma unroll
      for (int mf = 0; mf < 4; ++mf)
        #pragma unroll
        for (int nf = 0; nf < 4; ++nf)
          acc[4 + mf][nf] = MFMA16(frA[kk][mf], frB[kk][nf], acc[4 + mf][nf]);
    __builtin_amdgcn_s_setprio(0);
    if (X + 1 < NKT) {
      if (X + 2 < NKT) asm volatile("s_waitcnt vmcnt(4)" ::: "memory");
      else             asm volatile("s_waitcnt vmcnt(0)" ::: "memory");
      __builtin_amdgcn_sched_barrier(0);
    }
    __builtin_amdgcn_s_barrier();
  }
#undef STGU
#undef RD

  constexpr size_t PSTRIDE = (EPI == 4) ? (size_t)1024*512 : (size_t)2048*512;
  u16* outp = (EPI == 4 || EPI == 5) ? obf + (size_t)zz * PSTRIDE : obf;
  #pragma unroll
  for (int mf = 0; mf < 8; ++mf) {
    const int rbase = m0 + wm*128 + mf*16 + lhi*4;
    #pragma unroll
    for (int nf = 0; nf < 4; ++nf) {
      const int col = n0 + wn*64 + nf*16 + lrow;
      #pragma unroll
      for (int rr = 0; rr < 4; ++rr) {
        const int row = rbase + rr;
        float v = acc[mf][nf][rr];
        if (EPI == 1 || EPI == 2) {
          const float r = rout[(size_t)row*8 + (col >> 11)];
          outp[(size_t)row*16384 + col] = f2bf(fmaxf(v + bias[col], 0.f) * r);
        } else {
          outp[(size_t)row*512 + col] = f2bf(v);
        }
      }
    }
  }
}

// -------- combine: out_row += sum_z P_z + sum_e r_e b2 -----------------------
template<int Z>
__global__ __launch_bounds__(256) void combineZ_k(
    float* __restrict__ outq, const u16* __restrict__ P, size_t pstride,
    const float* __restrict__ routq, const float* __restrict__ b2)
{
  const int row = blockIdx.x, t = threadIdx.x;
  const int c = t * 2;
  float r[8];
  #pragma unroll
  for (int e = 0; e < 8; ++e) r[e] = routq[(size_t)row*8 + e];
  float v0 = outq[(size_t)row*512 + c];
  float v1 = outq[(size_t)row*512 + c + 1];
  #pragma unroll
  for (int z = 0; z < Z; ++z) {
    const unsigned pv = *(const unsigned*)(P + (size_t)z*pstride + (size_t)row*512 + c);
    v0 += bf2f((u16)(pv & 0xffffu));
    v1 += bf2f((u16)(pv >> 16));
  }
  #pragma unroll
  for (int e = 0; e < 8; ++e) {
    v0 += r[e] * b2[(size_t)e*512 + c];
    v1 += r[e] * b2[(size_t)e*512 + c + 1];
  }
  outq[(size_t)row*512 + c]     = v0;
  outq[(size_t)row*512 + c + 1] = v1;
}

// -------- fallback GEMM2 (pathB) ---------------------------------------------
__global__ __launch_bounds__(256) void gemm2_k(
    const u16* __restrict__ hid, const u16* __restrict__ w2t,
    u16* __restrict__ P, int e0, int accum)
{
  __shared__ u16 Asm[128*64];
  __shared__ u16 Bsm[64*64];
  const int t = threadIdx.x;
  const int l = t & 63;
  const int wid = t >> 6, wr = wid >> 1, wc = wid & 1;
  const int lrow = l & 15, lhi = l >> 4;
  const int m0 = blockIdx.x * 128, n0 = blockIdx.y * 64, z = blockIdx.z;

  const u16* A  = hid + z * 2048;
  const u16* Bt = w2t + (size_t)(e0 + z) * 512 * 2048;
  u16* Pz = P + (size_t)z * 4096 * 512;

  const f32x4 z4 = {0.f, 0.f, 0.f, 0.f};
  f32x4 acc[4][2];
  #pragma unroll
  for (int i = 0; i < 4; ++i) { acc[i][0] = z4; acc[i][1] = z4; }

  const u16* ga = A  + (size_t)(m0 + (t >> 3)) * 4096 + (t & 7) * 8;
  const u16* gb = Bt + (size_t)(n0 + (t >> 3)) * 2048 + (t & 7) * 8;

  for (int k0 = 0; k0 < 2048; k0 += 64) {
    #pragma unroll
    for (int i = 0; i < 4; ++i)
      GLDS16(ga + (size_t)i*32*4096 + k0, (char*)Asm + i*4096 + t*16);
    #pragma unroll
    for (int i = 0; i < 2; ++i)
      GLDS16(gb + (size_t)i*32*2048 + k0, (char*)Bsm + i*4096 + t*16);
    __syncthreads();
    #pragma unroll
    for (int kh = 0; kh < 2; ++kh) {
      s16x8 af[4], bfr[2];
      #pragma unroll
      for (int i = 0; i < 4; ++i)
        af[i]  = *(const s16x8*)(Asm + (wr*64 + i*16 + lrow)*64 + kh*32 + lhi*8);
      #pragma unroll
      for (int j = 0; j < 2; ++j)
        bfr[j] = *(const s16x8*)(Bsm + (wc*32 + j*16 + lrow)*64 + kh*32 + lhi*8);
      #pragma unroll
      for (int i = 0; i < 4; ++i)
        #pragma unroll
        for (int j = 0; j < 2; ++j)
          acc[i][j] = MFMA16(af[i], bfr[j], acc[i][j]);
    }
    __syncthreads();
  }

  #pragma unroll
  for (int i = 0; i < 4; ++i) {
    const int rbase = m0 + wr*64 + i*16 + lhi*4;
    #pragma unroll
    for (int j = 0; j < 2; ++j) {
      const int col = n0 + wc*32 + j*16 + lrow;
      #pragma unroll
      for (int rr = 0; rr < 4; ++rr) {
        const size_t idx = (size_t)(rbase + rr) * 512 + col;
        const float old = accum ? bf2f(Pz[idx]) : 0.f;
        Pz[idx] = f2bf(old + acc[i][j][rr]);
      }
    }
  }
}

// -------- fallback combine ---------------------------------------------------
__global__ __launch_bounds__(256) void combineB_k(
    float* __restrict__ out, const u16* __restrict__ P,
    const float* __restrict__ rout, const float* __restrict__ b2)
{
  const int row = blockIdx.x, t = threadIdx.x;
  float r[8];
  #pragma unroll
  for (int e = 0; e < 8; ++e) r[e] = rout[(size_t)row*8 + e];
  #pragma unroll
  for (int cc = 0; cc < 2; ++cc) {
    const int c = t + cc*256;
    const size_t idx = (size_t)row*512 + c;
    float v = out[idx] + bf2f(P[idx]) + bf2f(P[(size_t)4096*512 + idx]);
    #pragma unroll
    for (int e = 0; e < 8; ++e) v += r[e] * b2[(size_t)e*512 + c];
    out[idx] = v;
  }
}

// -------- flash attention: KVBLK=128, paired q-blocks {qp,15-qp}, 256 blk ----
__global__ __launch_bounds__(256) void attn_k(
    const u16* __restrict__ qkv, const u16* __restrict__ vt, u16* __restrict__ o)
{
  const int bid = blockIdx.x;
  const int xcd = bid & 7, rr_ = bid >> 3;
  const int bh = (rr_ >> 3) * 8 + xcd;
  const int qp = rr_ & 7;
  const int b = bh >> 3, h = bh & 7;
  const int t = threadIdx.x, l = t & 63, w = t >> 6;
  const int lrow = l & 15, lhi = l >> 4;

  __shared__ u16 Ksm[2][128*64];
  __shared__ u16 Vsm[2][64*128];
  __shared__ u16 Psm[4][16][136];

  const int trow = t >> 3;
  const int csw = ((t & 7) ^ (trow & 7)) * 8;
  const int vrow = t >> 4;
  const int vsw = ((t & 15) ^ (vrow & 7)) * 8;
  const u16* gk = qkv + (size_t)(b*1024 + trow) * 1536 + 512 + h*64 + csw;
  const u16* gv = vt + (size_t)bh*65536 + (size_t)vrow*1024 + vsw;
  const f32x4 z4 = {0.f,0.f,0.f,0.f};

#define ASTAGE(buf, s0) do { \
    _Pragma("unroll") \
    for (int i = 0; i < 4; ++i) \
      GLDS16(gk + (size_t)((s0) + i*32) * 1536, (char*)Ksm[buf] + i*4096 + t*16); \
    _Pragma("unroll") \
    for (int i = 0; i < 4; ++i) \
      GLDS16(gv + (s0) + (size_t)(i*16)*1024,   (char*)Vsm[buf] + i*4096 + t*16); \
  } while (0)

  for (int pass = 0; pass < 2; ++pass) {
    const int qb = pass ? (15 - qp) : qp;
    const int t0w = qb*64 + w*16;
    const u16* qrow = qkv + (size_t)(b*1024 + t0w + lrow) * 1536 + h*64 + lhi*8;
    s16x8 qf0 = *(const s16x8*)qrow;
    s16x8 qf1 = *(const s16x8*)(qrow + 32);

    float m[4], sl[4];
    f32x4 oacc[4];
    #pragma unroll
    for (int i = 0; i < 4; ++i) { m[i] = -1e30f; sl[i] = 0.f; oacc[i] = z4; }

    const int nt = (qb >> 1) + 1;
    ASTAGE(0, 0);
    for (int kv = 0; kv < nt; ++kv) {
      const int s0 = kv * 128;
      if (kv + 1 < nt) {
        ASTAGE((kv + 1) & 1, s0 + 128);
        asm volatile("s_waitcnt vmcnt(8)" ::: "memory");
      } else {
        asm volatile("s_waitcnt vmcnt(0)" ::: "memory");
      }
      __builtin_amdgcn_s_barrier();
      __builtin_amdgcn_sched_barrier(0);
      const u16* Ks = Ksm[kv & 1];
      const u16* Vs = Vsm[kv & 1];

      f32x4 sacc[8];
      #pragma unroll
      for (int n = 0; n < 8; ++n) sacc[n] = z4;
      #pragma unroll
      for (int n = 0; n < 8; ++n) {
        const int r = n*16 + lrow;
        s16x8 kf0 = *(const s16x8*)((const char*)Ks + r*128 + ((lhi*16) ^ ((r & 7) << 4)));
        s16x8 kf1 = *(const s16x8*)((const char*)Ks + r*128 + ((64 + lhi*16) ^ ((r & 7) << 4)));
        sacc[n] = MFMA16(qf0, kf0, sacc[n]);
        sacc[n] = MFMA16(qf1, kf1, sacc[n]);
      }
      if (s0 + 127 > t0w) {
        #pragma unroll
        for (int n = 0; n < 8; ++n)
          #pragma unroll
          for (int rr = 0; rr < 4; ++rr)
            if (s0 + n*16 + lrow > t0w + lhi*4 + rr) sacc[n][rr] = -1e30f;
      }
      float pm[4];
      #pragma unroll
      for (int rr = 0; rr < 4; ++rr) {
        float a = fmaxf(fmaxf(sacc[0][rr], sacc[1][rr]), fmaxf(sacc[2][rr], sacc[3][rr]));
        float bmx = fmaxf(fmaxf(sacc[4][rr], sacc[5][rr]), fmaxf(sacc[6][rr], sacc[7][rr]));
        pm[rr] = fmaxf(a, bmx);
      }
      #pragma unroll
      for (int rr = 0; rr < 4; ++rr) {
        pm[rr] = fmaxf(pm[rr], __shfl_xor(pm[rr], 1));
        pm[rr] = fmaxf(pm[rr], __shfl_xor(pm[rr], 2));
        pm[rr] = fmaxf(pm[rr], __shfl_xor(pm[rr], 4));
        pm[rr] = fmaxf(pm[rr], __shfl_xor(pm[rr], 8));
      }
      float p[8][4], ps[4], scv[4];
      #pragma unroll
      for (int rr = 0; rr < 4; ++rr) {
        const float mn = fmaxf(m[rr], pm[rr]);
        scv[rr] = __expf(m[rr] - mn);
        m[rr] = mn;
        ps[rr] = 0.f;
        #pragma unroll
        for (int n = 0; n < 8; ++n) {
          p[n][rr] = __expf(sacc[n][rr] - mn);
          ps[rr] += p[n][rr];
        }
      }
      #pragma unroll
      for (int rr = 0; rr < 4; ++rr) {
        ps[rr] += __shfl_xor(ps[rr], 1);
        ps[rr] += __shfl_xor(ps[rr], 2);
        ps[rr] += __shfl_xor(ps[rr], 4);
        ps[rr] += __shfl_xor(ps[rr], 8);
        sl[rr] = sl[rr] * scv[rr] + ps[rr];
      }
      #pragma unroll
      for (int ct = 0; ct < 4; ++ct) {
        f32x4 t4 = oacc[ct];
        #pragma unroll
        for (int rr = 0; rr < 4; ++rr) t4[rr] *= scv[rr];
        oacc[ct] = t4;
      }
      #pragma unroll
      for (int n = 0; n < 8; ++n)
        #pragma unroll
        for (int rr = 0; rr < 4; ++rr)
          Psm[w][lhi*4 + rr][n*16 + lrow] = f2bf(p[n][rr]);
      asm volatile("s_waitcnt lgkmcnt(0)" ::: "memory");
      __builtin_amdgcn_sched_barrier(0);
      s16x8 pa[4];
      #pragma unroll
      for (int s = 0; s < 4; ++s)
        pa[s] = *(const s16x8*)&Psm[w][lrow][s*32 + lhi*8];
      #pragma unroll
      for (int ct = 0; ct < 4; ++ct) {
        const int r = ct*16 + lrow;
        #pragma unroll
        for (int s = 0; s < 4; ++s) {
          s16x8 vb = *(const s16x8*)((const char*)Vs + r*256 + ((s*64 + lhi*16) ^ ((r & 7) << 4)));
          oacc[ct] = MFMA16(pa[s], vb, oacc[ct]);
        }
      }
      __builtin_amdgcn_s_barrier();
      __builtin_amdgcn_sched_barrier(0);
    }
    #pragma unroll
    for (int ct = 0; ct < 4; ++ct)
      #pragma unroll
      for (int rr = 0; rr < 4; ++rr) {
        const int row = b*1024 + t0w + lhi*4 + rr;
        o[(size_t)row*512 + h*64 + ct*16 + lrow] = f2bf(oacc[ct][rr] / sl[rr]);
      }
  }
#undef ASTAGE
}

// -------- fused LN2 + router (fp32 exact top-2) + h2 bf16 output -------------
__global__ __launch_bounds__(256) void router_k(
    const float* __restrict__ x2, const float* __restrict__ g,
    const float* __restrict__ b, const float* __restrict__ Wr,
    const float* __restrict__ br, float* __restrict__ rt,
    u16* __restrict__ h2o)
{
  const int l = threadIdx.x & 63, w = threadIdx.x >> 6;
  const int tkn = blockIdx.x * 4 + w;
  const float* xr = x2 + (size_t)tkn * 512;
  float v[8];
  float s = 0.f, ss = 0.f;
  #pragma unroll
  for (int i = 0; i < 8; ++i) {
    v[i] = xr[l*8 + i];
    s += v[i]; ss += v[i]*v[i];
  }
  #pragma unroll
  for (int off = 1; off < 64; off <<= 1) {
    s  += __shfl_xor(s, off);
    ss += __shfl_xor(ss, off);
  }
  const float mu = s * (1.f/512.f);
  const float var = ss * (1.f/512.f) - mu*mu;
  const float rstd = rsqrtf(var + 1e-5f);
  float acc[8];
  #pragma unroll
  for (int e = 0; e < 8; ++e) acc[e] = 0.f;
  s16x8 hw;
  #pragma unroll
  for (int i = 0; i < 8; ++i) {
    const int c = l*8 + i;
    const float hv = (v[i] - mu) * rstd * g[c] + b[c];
    hw[i] = (short)f2bf(hv);
    const float* wrow = Wr + (size_t)c * 8;
    #pragma unroll
    for (int e = 0; e < 8; ++e) acc[e] += hv * wrow[e];
  }
  *(s16x8*)(h2o + (size_t)tkn*512 + l*8) = hw;
  #pragma unroll
  for (int e = 0; e < 8; ++e) {
    #pragma unroll
    for (int off = 1; off < 64; off <<= 1) acc[e] += __shfl_xor(acc[e], off);
    acc[e] += br[e];
  }
  int e1 = 0;
  #pragma unroll
  for (int e = 1; e < 8; ++e) if (acc[e] > acc[e1]) e1 = e;
  int e2 = (e1 == 0) ? 1 : 0;
  #pragma unroll
  for (int e = 0; e < 8; ++e) if (e != e1 && acc[e] > acc[e2]) e2 = e;
  const float mx = fmaxf(acc[e1], 0.f);
  float Z = 0.f;
  #pragma unroll
  for (int e = 0; e < 8; ++e) {
    const float mv = (e == e1 || e == e2) ? acc[e] : 0.f;
    Z += __expf(mv - mx);
  }
  if (l < 8) {
    const float mv = (l == e1 || l == e2) ? acc[l] : 0.f;
    rt[(size_t)tkn * 8 + l] = __expf(mv - mx) / Z;
  }
}

extern "C" void kernel_launch(void* const* d_in, const int* in_sizes, int n_in,
                              void* d_out, int out_size, void* d_ws, size_t ws_size,
                              hipStream_t stream) {
  const float* x    = (const float*)d_in[0];
  const float* ln1g = (const float*)d_in[1];
  const float* ln1b = (const float*)d_in[2];
  const float* ln2g = (const float*)d_in[3];
  const float* ln2b = (const float*)d_in[4];
  const float* Wq   = (const float*)d_in[5];
  const float* Wk   = (const float*)d_in[6];
  const float* Wv   = (const float*)d_in[7];
  const float* Wp   = (const float*)d_in[8];
  const float* bp   = (const float*)d_in[9];
  const float* Wr   = (const float*)d_in[10];
  const float* br   = (const float*)d_in[11];
  const float* W1   = (const float*)d_in[12];
  const float* b1   = (const float*)d_in[13];
  const float* W2   = (const float*)d_in[14];
  const float* b2   = (const float*)d_in[15];
  float* out = (float*)d_out;

  const int pathH = (ws_size >= (size_t)138543104) ? 1 : 0;  // halves MoE
  const int pathN = (ws_size >= (size_t)104988672) ? 1 : 0;  // quarters MoE

  char* ws = (char*)d_ws;
  size_t off = 0;
  auto alloc = [&](size_t bytes) -> char* {
    char* p = ws + off;
    off += (bytes + 255) & ~(size_t)255;
    return p;
  };
  u16* w1_t = (u16*)alloc((size_t)8*2048*512*2);   // flat [16384][512]
  u16* w2f  = (u16*)alloc((size_t)8*512*2048*2);   // flat [512][16384] (pathN/H)
  u16* h2b  = (u16*)alloc((size_t)4096*512*2);
  float* rout = (float*)alloc((size_t)4096*8*4);
  u16* hidq = (u16*)alloc(pathH ? (size_t)2048*16384*2 : (size_t)4096*4096*2);
  u16* Ppl  = (u16*)alloc(pathH ? (size_t)16*2048*512*2
                                : (pathN ? (size_t)32*1024*512*2 : (size_t)2*4096*512*2));
  // attention-phase overlays inside hidq (>=32 MiB region, dead before MoE):
  u16* wqkv_t = (u16*)hidq;                          // 1.5 MiB
  u16* wp_t   = (u16*)((char*)hidq + 1572864);       // 0.5 MiB
  u16* hb     = (u16*)((char*)hidq + 2097152);       // 4 MiB
  u16* attnb  = (u16*)((char*)hidq + 6291456);       // 4 MiB
  u16* qkvb   = (u16*)((char*)hidq + 10485760);      // 12 MiB
  u16* vtb    = (u16*)((char*)hidq + 23068672);      // 8 MiB (ends 30 MiB)

  const dim3 tb(32, 8);
  transqkv_k<<<dim3(2,16,32), tb, 0, stream>>>(Wq, Wk, Wv, Wp, wqkv_t, wp_t);
  if (pathN) {
    transW_k<<<dim3(64,16,16), tb, 0, stream>>>(W1, W2, w1_t, w2f);
  } else {
    transpose_k<<<dim3(64,16,8), tb, 0, stream>>>(W1, w1_t, 512, 2048,
        (long long)512*2048, (long long)2048*512, 1.f);
    transpose_k<<<dim3(16,64,8), tb, 0, stream>>>(W2, w2f, 2048, 512,
        (long long)2048*512, (long long)512*2048, 1.f);
  }

  ln_k<<<4096, 256, 0, stream>>>(x, ln1g, ln1b, hb);
  gemm2p<96,0><<<dim3(32,16), 256, 0, stream>>>(hb, wqkv_t, 4096, 1536, 512, 512, 512,
                                                qkvb, nullptr, nullptr, nullptr, 0);
  vtrans_k<<<dim3(32,2,32), tb, 0, stream>>>(qkvb, vtb);
  attn_k<<<256, 256, 0, stream>>>(qkvb, vtb, attnb);
  gemm2p<64,2><<<dim3(32,8), 256, 0, stream>>>(attnb, wp_t, 4096, 512, 512, 512, 512,
                                               nullptr, out, bp, x, 0);
  router_k<<<1024, 256, 0, stream>>>(out, ln2g, ln2b, Wr, br, rout, h2b);

  if (pathH) {
    for (int h = 0; h < 2; ++h) {
      // G1: gemm1s 256x64, 2048 blocks, 3-4 blocks/CU (new structure probe)
      gemm1s<<<2048, 256, 0, stream>>>(h2b + (size_t)h*2048*512, w1_t,
                                       hidq, b1, rout + (size_t)h*16384);
      gemm8p<16,5><<<256, 512, 0, stream>>>(hidq, w2f, 16384, 16384,
                                            Ppl, nullptr, nullptr);
      combineZ_k<16><<<2048, 256, 0, stream>>>(out + (size_t)h*2048*512, Ppl,
                                               (size_t)2048*512,
                                               rout + (size_t)h*16384, b2);
    }
  } else if (pathN) {
    for (int q = 0; q < 4; ++q) {
      gemm8p<8,1><<<256, 512, 0, stream>>>(h2b + (size_t)q*1024*512, w1_t, 512, 512,
                                           hidq, b1, rout + (size_t)q*8192);
      gemm8p<8,4><<<256, 512, 0, stream>>>(hidq, w2f, 16384, 16384,
                                           Ppl, nullptr, nullptr);
      combineZ_k<32><<<1024, 256, 0, stream>>>(out + (size_t)q*1024*512, Ppl,
                                               (size_t)1024*512,
                                               rout + (size_t)q*8192, b2);
    }
  } else {
    for (int p = 0; p < 4; ++p) {
      const int e0 = 2*p;
      gemm2p<128,1><<<dim3(32,32), 256, 0, stream>>>(h2b, w1_t + (size_t)e0*2048*512,
                                                     4096, 4096, 512, 512, 512,
                                                     hidq, nullptr, b1 + (size_t)e0*2048, rout, e0);
      gemm2_k<<<dim3(32,8,2), 256, 0, stream>>>(hidq, w2f, Ppl, e0, p > 0 ? 1 : 0);
    }
    combineB_k<<<4096, 256, 0, stream>>>(out, Ppl, rout, b2);
  }
}

// Round 17
// 266.907 us; speedup vs baseline: 1.0353x; 1.0353x over previous
//
#include <hip/hip_runtime.h>

// B=4, T=1024, C=512, H=8, HD=64, NE=8, K(topk)=2, FF=2048
// Round-17: terminal config = r15 best (269.2us). G1 reverted to gemm8p
// (gemm1s probe was 54us vs 51us). MoE structure space closed after 5
// bracketing designs all land 51-63us (~675 TF plateau at short K).
// Attention KVBLK=128, merged preps, fused LN2+router, BN=96 QKV.

typedef unsigned short u16;
typedef __attribute__((ext_vector_type(8))) short s16x8;
typedef __attribute__((ext_vector_type(4))) float f32x4;

__device__ __forceinline__ u16 f2bf(float f) {
  union { float f; unsigned u; } v; v.f = f;
  unsigned r = v.u + 0x7fffu + ((v.u >> 16) & 1u);  // RNE
  return (u16)(r >> 16);
}
__device__ __forceinline__ float bf2f(u16 h) {
  union { unsigned u; float f; } v; v.u = ((unsigned)h) << 16;
  return v.f;
}

#define GLDS16(g, s) __builtin_amdgcn_global_load_lds( \
    (const __attribute__((address_space(1))) void*)(g), \
    (__attribute__((address_space(3))) void*)(s), 16, 0, 0)

#define MFMA16(a, b, c) __builtin_amdgcn_mfma_f32_16x16x32_bf16((a), (b), (c), 0, 0, 0)

// -------- transpose + fp32->bf16 convert: in [R][C] fp32 -> out [C][R] bf16 --
__global__ __launch_bounds__(256) void transpose_k(
    const float* __restrict__ in, u16* __restrict__ out,
    int R, int C, long long ibs, long long obs, float scale)
{
  __shared__ float tile[32][33];
  in  += (long long)blockIdx.z * ibs;
  out += (long long)blockIdx.z * obs;
  const int c0 = blockIdx.x * 32, r0 = blockIdx.y * 32;
  const int tx = threadIdx.x, ty = threadIdx.y;  // (32,8)
  #pragma unroll
  for (int i = 0; i < 4; ++i)
    tile[ty + i*8][tx] = in[(size_t)(r0 + ty + i*8) * C + c0 + tx];
  __syncthreads();
  #pragma unroll
  for (int i = 0; i < 4; ++i)
    out[(size_t)(c0 + ty + i*8) * R + r0 + tx] = f2bf(tile[tx][ty + i*8] * scale);
}

// -------- merged W1+W2 prep: z<8 = W1 e=z; z>=8 = W2 e=z-8 -> flat [512][16384]
__global__ __launch_bounds__(256) void transW_k(
    const float* __restrict__ W1, const float* __restrict__ W2,
    u16* __restrict__ w1t, u16* __restrict__ w2f)
{
  __shared__ float tile[32][33];
  const int z = blockIdx.z;
  const int tx = threadIdx.x, ty = threadIdx.y;
  if (z < 8) {
    const float* in = W1 + (size_t)z * 512 * 2048;
    u16* out = w1t + (size_t)z * 2048 * 512;
    const int c0 = blockIdx.x * 32, r0 = blockIdx.y * 32;
    #pragma unroll
    for (int i = 0; i < 4; ++i)
      tile[ty + i*8][tx] = in[(size_t)(r0 + ty + i*8) * 2048 + c0 + tx];
    __syncthreads();
    #pragma unroll
    for (int i = 0; i < 4; ++i)
      out[(size_t)(c0 + ty + i*8) * 512 + r0 + tx] = f2bf(tile[tx][ty + i*8]);
  } else {
    const int e = z - 8;
    const float* in = W2 + (size_t)e * 2048 * 512;
    const int r0 = blockIdx.x * 32, c0 = blockIdx.y * 32;
    #pragma unroll
    for (int i = 0; i < 4; ++i)
      tile[ty + i*8][tx] = in[(size_t)(r0 + ty + i*8) * 512 + c0 + tx];
    __syncthreads();
    #pragma unroll
    for (int i = 0; i < 4; ++i)
      w2f[(size_t)(c0 + ty + i*8) * 16384 + e*2048 + r0 + tx] = f2bf(tile[tx][ty + i*8]);
  }
}

// -------- merged Wq/Wk/Wv (+Wp) transpose ------------------------------------
__global__ __launch_bounds__(256) void transqkv_k(
    const float* __restrict__ Wq, const float* __restrict__ Wk,
    const float* __restrict__ Wv, const float* __restrict__ Wp,
    u16* __restrict__ oqkv, u16* __restrict__ owp)
{
  __shared__ float tile[32][33];
  const int z = blockIdx.z;
  const int tx = threadIdx.x, ty = threadIdx.y;
  if (z < 24) {
    const int which = z >> 3, head = z & 7;
    const float* in = (which == 0 ? Wq : (which == 1 ? Wk : Wv)) + (size_t)head * 512 * 64;
    u16* o = oqkv + (size_t)which * 512 * 512 + (size_t)head * 64 * 512;
    const float scale = (which == 0) ? 0.125f : 1.f;
    const int c0 = blockIdx.x * 32, r0 = blockIdx.y * 32;
    #pragma unroll
    for (int i = 0; i < 4; ++i)
      tile[ty + i*8][tx] = in[(size_t)(r0 + ty + i*8) * 64 + c0 + tx];
    __syncthreads();
    #pragma unroll
    for (int i = 0; i < 4; ++i)
      o[(size_t)(c0 + ty + i*8) * 512 + r0 + tx] = f2bf(tile[tx][ty + i*8] * scale);
  } else {
    const int zz = z - 24;
    const int c0 = (zz * 2 + blockIdx.x) * 32;
    const int r0 = blockIdx.y * 32;
    #pragma unroll
    for (int i = 0; i < 4; ++i)
      tile[ty + i*8][tx] = Wp[(size_t)(r0 + ty + i*8) * 512 + c0 + tx];
    __syncthreads();
    #pragma unroll
    for (int i = 0; i < 4; ++i)
      owp[(size_t)(c0 + ty + i*8) * 512 + r0 + tx] = f2bf(tile[tx][ty + i*8]);
  }
}

// -------- V transpose: qkv V-section -> vt[bh][64 d][1024 t] bf16 ------------
__global__ __launch_bounds__(256) void vtrans_k(
    const u16* __restrict__ qkv, u16* __restrict__ vt)
{
  __shared__ u16 tile[32][33];
  const int bh = blockIdx.z, b = bh >> 3, h = bh & 7;
  const int t0 = blockIdx.x * 32, d0 = blockIdx.y * 32;
  const int tx = threadIdx.x, ty = threadIdx.y;
  #pragma unroll
  for (int i = 0; i < 4; ++i)
    tile[ty + i*8][tx] = qkv[(size_t)(b*1024 + t0 + ty + i*8) * 1536 + 1024 + h*64 + d0 + tx];
  __syncthreads();
  #pragma unroll
  for (int i = 0; i < 4; ++i)
    vt[(size_t)bh*65536 + (size_t)(d0 + ty + i*8) * 1024 + t0 + tx] = tile[tx][ty + i*8];
}

// -------- LayerNorm (C=512): fp32 in -> bf16 out -----------------------------
__global__ __launch_bounds__(256) void ln_k(
    const float* __restrict__ x, const float* __restrict__ g,
    const float* __restrict__ b, u16* __restrict__ o)
{
  const int row = blockIdx.x, t = threadIdx.x;
  const float* xr = x + (size_t)row * 512;
  const float a0 = xr[t], a1 = xr[t + 256];
  float s = a0 + a1, ss = a0*a0 + a1*a1;
  #pragma unroll
  for (int off = 1; off < 64; off <<= 1) {
    s  += __shfl_xor(s, off);
    ss += __shfl_xor(ss, off);
  }
  __shared__ float rs[4], rq[4];
  const int w = t >> 6;
  if ((t & 63) == 0) { rs[w] = s; rq[w] = ss; }
  __syncthreads();
  s  = rs[0] + rs[1] + rs[2] + rs[3];
  ss = rq[0] + rq[1] + rq[2] + rq[3];
  const float mu = s * (1.f/512.f);
  const float var = ss * (1.f/512.f) - mu*mu;
  const float rstd = rsqrtf(var + 1e-5f);
  o[(size_t)row*512 + t]       = f2bf((a0 - mu) * rstd * g[t]     + b[t]);
  o[(size_t)row*512 + t + 256] = f2bf((a1 - mu) * rstd * g[t+256] + b[t+256]);
}

// -------- gemm2p: 128xBN BK=64, 4 waves, dbuf, counted vmcnt, LDS swizzle ----
template<int BN, int EPI>
__global__ __launch_bounds__(256) void gemm2p(
    const u16* __restrict__ A, const u16* __restrict__ Bt,
    int M, int N, int K, int lda, int ldb,
    u16* __restrict__ obf, float* __restrict__ oa,
    const float* __restrict__ bias, const float* __restrict__ extra, int e0)
{
  constexpr int NB = BN / 32;
  constexpr int SB = BN / 32;
  __shared__ u16 Asm[2][128*64];
  __shared__ u16 Bsm[2][BN*64];
  const int t = threadIdx.x, l = t & 63;
  const int wid = t >> 6, wr = wid >> 1, wc = wid & 1;
  const int lrow = l & 15, lhi = l >> 4;
  const int m0 = blockIdx.x * 128, n0 = blockIdx.y * BN;

  const f32x4 z4 = {0.f, 0.f, 0.f, 0.f};
  f32x4 acc[4][NB];
  #pragma unroll
  for (int i = 0; i < 4; ++i)
    #pragma unroll
    for (int j = 0; j < NB; ++j) acc[i][j] = z4;

  const int csw = ((t & 7) ^ ((t >> 3) & 7)) * 8;
  const u16* ga = A  + (size_t)(m0 + (t >> 3)) * lda + csw;
  const u16* gb = Bt + (size_t)(n0 + (t >> 3)) * ldb + csw;

#define STG2(buf, k0) do { \
    _Pragma("unroll") \
    for (int i = 0; i < 4; ++i) \
      GLDS16(ga + (size_t)(i*32)*lda + (k0), (char*)Asm[buf] + i*4096 + t*16); \
    _Pragma("unroll") \
    for (int i = 0; i < SB; ++i) \
      GLDS16(gb + (size_t)(i*32)*ldb + (k0), (char*)Bsm[buf] + i*4096 + t*16); \
  } while (0)

#define RD2(Ls, row, kb) (*(const s16x8*)((const char*)(Ls) + (row)*128 + ((kb) ^ (((row)&7)<<4))))

  const int NT = K >> 6;
  STG2(0, 0);
  for (int tt = 0; tt < NT; ++tt) {
    if (tt + 1 < NT) {
      STG2((tt + 1) & 1, (tt + 1) * 64);
      if constexpr (BN == 128)     asm volatile("s_waitcnt vmcnt(8)" ::: "memory");
      else if constexpr (BN == 96) asm volatile("s_waitcnt vmcnt(7)" ::: "memory");
      else                         asm volatile("s_waitcnt vmcnt(6)" ::: "memory");
    } else {
      asm volatile("s_waitcnt vmcnt(0)" ::: "memory");
    }
    __builtin_amdgcn_sched_barrier(0);
    __builtin_amdgcn_s_barrier();
    const u16* As = Asm[tt & 1];
    const u16* Bs = Bsm[tt & 1];
    #pragma unroll
    for (int kh = 0; kh < 2; ++kh) {
      s16x8 af[4], bfr[NB];
      #pragma unroll
      for (int i = 0; i < 4; ++i)
        af[i]  = RD2(As, wr*64 + i*16 + lrow, kh*64 + lhi*16);
      #pragma unroll
      for (int j = 0; j < NB; ++j)
        bfr[j] = RD2(Bs, wc*(BN/2) + j*16 + lrow, kh*64 + lhi*16);
      #pragma unroll
      for (int i = 0; i < 4; ++i)
        #pragma unroll
        for (int j = 0; j < NB; ++j)
          acc[i][j] = MFMA16(af[i], bfr[j], acc[i][j]);
    }
    __builtin_amdgcn_s_barrier();
    __builtin_amdgcn_sched_barrier(0);
  }
#undef STG2
#undef RD2

  #pragma unroll
  for (int i = 0; i < 4; ++i) {
    const int rbase = m0 + wr*64 + i*16 + lhi*4;
    #pragma unroll
    for (int j = 0; j < NB; ++j) {
      const int col = n0 + wc*(BN/2) + j*16 + lrow;
      #pragma unroll
      for (int rr = 0; rr < 4; ++rr) {
        const int row = rbase + rr;
        const float v = acc[i][j][rr];
        if (EPI == 0) {
          obf[(size_t)row*N + col] = f2bf(v);
        } else if (EPI == 1) {
          const float r = extra[(size_t)row*8 + e0 + (col >> 11)];
          obf[(size_t)row*N + col] = f2bf(fmaxf(v + bias[col], 0.f) * r);
        } else {
          oa[(size_t)row*N + col] = v + bias[col] + extra[(size_t)row*N + col];
        }
      }
    }
  }
}

// -------- gemm8p: 256x256, 8 waves (2x4), BK=64, 2-phase/K-tile (r12 best) ---
template<int NKT, int EPI>
__global__ __launch_bounds__(512, 2) void gemm8p(
    const u16* __restrict__ A, const u16* __restrict__ Bt,
    int lda, int ldb,
    u16* __restrict__ obf,
    const float* __restrict__ bias, const float* __restrict__ rout)
{
  __shared__ u16 Lds[2][2][256*64];   // 128 KiB
  const int t = threadIdx.x, l = t & 63;
  const int wid = t >> 6, wm = wid >> 2, wn = wid & 3;
  const int lrow = l & 15, lhi = l >> 4;

  int m0, n0, zz = 0;
  {
    const int bid = blockIdx.x;
    const int r = bid & 7, k = bid >> 3;
    if (EPI == 1) {
      m0 = (k >> 3) * 256; n0 = (r * 8 + (k & 7)) * 256;
    } else if (EPI == 2) {
      n0 = (r * 8 + (k & 7)) * 256; m0 = (k >> 3) * 256;
    } else if (EPI == 4) {
      zz = r*4 + (k & 3);
      const int mn = k >> 2;
      m0 = (mn >> 1) * 256; n0 = (mn & 1) * 256;
    } else {
      zz = r*2 + (k & 1);
      const int mn = k >> 1;
      m0 = (mn >> 1) * 256; n0 = (mn & 1) * 256;
    }
  }
  constexpr int KCH = (EPI == 4) ? 512 : 1024;
  const u16* Ab = A  + (size_t)m0 * lda + ((EPI == 4 || EPI == 5) ? zz * KCH : 0);
  const u16* Bb = Bt + (size_t)n0 * ldb + ((EPI == 4 || EPI == 5) ? zz * KCH : 0);

  const int tr = t >> 3;
  const int sc = ((t & 7) ^ (tr & 7)) * 8;

#define STGU(bf, kt, op_, u4_) do { \
    const u16* s_ = (op_) ? Bb : Ab; \
    const int ld_ = (op_) ? ldb : lda; \
    GLDS16(s_ + (size_t)((u4_)*64 + tr) * ld_ + (size_t)(kt)*64 + sc, \
           (char*)&Lds[bf][op_][0] + (u4_)*8192 + t*16); \
  } while (0)

#define RD(Ls, row, kb) (*(const s16x8*)((const char*)(Ls) + (row)*128 + ((kb) ^ (((row)&7)<<4))))

  f32x4 acc[8][4];
  const f32x4 z4 = {0.f, 0.f, 0.f, 0.f};
  #pragma unroll
  for (int i = 0; i < 8; ++i)
    #pragma unroll
    for (int j = 0; j < 4; ++j) acc[i][j] = z4;

  #pragma unroll
  for (int u = 0; u < 4; ++u) STGU(0, 0, 0, u);
  #pragma unroll
  for (int u = 0; u < 4; ++u) STGU(0, 0, 1, u);
  if (NKT > 1) {
    #pragma unroll
    for (int u = 0; u < 4; ++u) STGU(1, 1, 1, u);
    asm volatile("s_waitcnt vmcnt(4)" ::: "memory");
  } else {
    asm volatile("s_waitcnt vmcnt(0)" ::: "memory");
  }
  __builtin_amdgcn_sched_barrier(0);
  __builtin_amdgcn_s_barrier();

  s16x8 frA[2][4], frB[2][4];
  #pragma unroll 2
  for (int X = 0; X < NKT; ++X) {
    const u16* As = &Lds[X & 1][0][0];
    const u16* Bs = &Lds[X & 1][1][0];
    // ---- phase 0 ----
    #pragma unroll
    for (int kk = 0; kk < 2; ++kk) {
      #pragma unroll
      for (int nf = 0; nf < 4; ++nf)
        frB[kk][nf] = RD(Bs, wn*64 + nf*16 + lrow, kk*64 + lhi*16);
      #pragma unroll
      for (int mf = 0; mf < 4; ++mf)
        frA[kk][mf] = RD(As, wm*128 + mf*16 + lrow, kk*64 + lhi*16);
    }
    if (X + 1 < NKT) {
      #pragma unroll
      for (int u = 0; u < 4; ++u) STGU((X + 1) & 1, X + 1, 0, u);
    }
    __builtin_amdgcn_s_barrier();
    asm volatile("s_waitcnt lgkmcnt(0)" ::: "memory");
    __builtin_amdgcn_sched_barrier(0);
    __builtin_amdgcn_s_setprio(1);
    #pragma unroll
    for (int kk = 0; kk < 2; ++kk)
      #pragma unroll
      for (int mf = 0; mf < 4; ++mf)
        #pragma unroll
        for (int nf = 0; nf < 4; ++nf)
          acc[mf][nf] = MFMA16(frA[kk][mf], frB[kk][nf], acc[mf][nf]);
    __builtin_amdgcn_s_setprio(0);
    __builtin_amdgcn_s_barrier();
    // ---- phase 1 ----
    #pragma unroll
    for (int kk = 0; kk < 2; ++kk)
      #pragma unroll
      for (int mf = 0; mf < 4; ++mf)
        frA[kk][mf] = RD(As, wm*128 + 64 + mf*16 + lrow, kk*64 + lhi*16);
    if (X + 2 < NKT) {
      #pragma unroll
      for (int u = 0; u < 4; ++u) STGU(X & 1, X + 2, 1, u);
    }
    __builtin_amdgcn_s_barrier();
    asm volatile("s_waitcnt lgkmcnt(0)" ::: "memory");
    __builtin_amdgcn_sched_barrier(0);
    __builtin_amdgcn_s_setprio(1);
    #pragma unroll
    for (int kk = 0; kk < 2; ++kk)
      #pragma unroll
      for (int mf = 0; mf < 4; ++mf)
        #pragma unroll
        for (int nf = 0; nf < 4; ++nf)
          acc[4 + mf][nf] = MFMA16(frA[kk][mf], frB[kk][nf], acc[4 + mf][nf]);
    __builtin_amdgcn_s_setprio(0);
    if (X + 1 < NKT) {
      if (X + 2 < NKT) asm volatile("s_waitcnt vmcnt(4)" ::: "memory");
      else             asm volatile("s_waitcnt vmcnt(0)" ::: "memory");
      __builtin_amdgcn_sched_barrier(0);
    }
    __builtin_amdgcn_s_barrier();
  }
#undef STGU
#undef RD

  constexpr size_t PSTRIDE = (EPI == 4) ? (size_t)1024*512 : (size_t)2048*512;
  u16* outp = (EPI == 4 || EPI == 5) ? obf + (size_t)zz * PSTRIDE : obf;
  #pragma unroll
  for (int mf = 0; mf < 8; ++mf) {
    const int rbase = m0 + wm*128 + mf*16 + lhi*4;
    #pragma unroll
    for (int nf = 0; nf < 4; ++nf) {
      const int col = n0 + wn*64 + nf*16 + lrow;
      #pragma unroll
      for (int rr = 0; rr < 4; ++rr) {
        const int row = rbase + rr;
        float v = acc[mf][nf][rr];
        if (EPI == 1 || EPI == 2) {
          const float r = rout[(size_t)row*8 + (col >> 11)];
          outp[(size_t)row*16384 + col] = f2bf(fmaxf(v + bias[col], 0.f) * r);
        } else {
          outp[(size_t)row*512 + col] = f2bf(v);
        }
      }
    }
  }
}

// -------- combine: out_row += sum_z P_z + sum_e r_e b2 -----------------------
template<int Z>
__global__ __launch_bounds__(256) void combineZ_k(
    float* __restrict__ outq, const u16* __restrict__ P, size_t pstride,
    const float* __restrict__ routq, const float* __restrict__ b2)
{
  const int row = blockIdx.x, t = threadIdx.x;
  const int c = t * 2;
  float r[8];
  #pragma unroll
  for (int e = 0; e < 8; ++e) r[e] = routq[(size_t)row*8 + e];
  float v0 = outq[(size_t)row*512 + c];
  float v1 = outq[(size_t)row*512 + c + 1];
  #pragma unroll
  for (int z = 0; z < Z; ++z) {
    const unsigned pv = *(const unsigned*)(P + (size_t)z*pstride + (size_t)row*512 + c);
    v0 += bf2f((u16)(pv & 0xffffu));
    v1 += bf2f((u16)(pv >> 16));
  }
  #pragma unroll
  for (int e = 0; e < 8; ++e) {
    v0 += r[e] * b2[(size_t)e*512 + c];
    v1 += r[e] * b2[(size_t)e*512 + c + 1];
  }
  outq[(size_t)row*512 + c]     = v0;
  outq[(size_t)row*512 + c + 1] = v1;
}

// -------- fallback GEMM2 (pathB) ---------------------------------------------
__global__ __launch_bounds__(256) void gemm2_k(
    const u16* __restrict__ hid, const u16* __restrict__ w2t,
    u16* __restrict__ P, int e0, int accum)
{
  __shared__ u16 Asm[128*64];
  __shared__ u16 Bsm[64*64];
  const int t = threadIdx.x;
  const int l = t & 63;
  const int wid = t >> 6, wr = wid >> 1, wc = wid & 1;
  const int lrow = l & 15, lhi = l >> 4;
  const int m0 = blockIdx.x * 128, n0 = blockIdx.y * 64, z = blockIdx.z;

  const u16* A  = hid + z * 2048;
  const u16* Bt = w2t + (size_t)(e0 + z) * 512 * 2048;
  u16* Pz = P + (size_t)z * 4096 * 512;

  const f32x4 z4 = {0.f, 0.f, 0.f, 0.f};
  f32x4 acc[4][2];
  #pragma unroll
  for (int i = 0; i < 4; ++i) { acc[i][0] = z4; acc[i][1] = z4; }

  const u16* ga = A  + (size_t)(m0 + (t >> 3)) * 4096 + (t & 7) * 8;
  const u16* gb = Bt + (size_t)(n0 + (t >> 3)) * 2048 + (t & 7) * 8;

  for (int k0 = 0; k0 < 2048; k0 += 64) {
    #pragma unroll
    for (int i = 0; i < 4; ++i)
      GLDS16(ga + (size_t)i*32*4096 + k0, (char*)Asm + i*4096 + t*16);
    #pragma unroll
    for (int i = 0; i < 2; ++i)
      GLDS16(gb + (size_t)i*32*2048 + k0, (char*)Bsm + i*4096 + t*16);
    __syncthreads();
    #pragma unroll
    for (int kh = 0; kh < 2; ++kh) {
      s16x8 af[4], bfr[2];
      #pragma unroll
      for (int i = 0; i < 4; ++i)
        af[i]  = *(const s16x8*)(Asm + (wr*64 + i*16 + lrow)*64 + kh*32 + lhi*8);
      #pragma unroll
      for (int j = 0; j < 2; ++j)
        bfr[j] = *(const s16x8*)(Bsm + (wc*32 + j*16 + lrow)*64 + kh*32 + lhi*8);
      #pragma unroll
      for (int i = 0; i < 4; ++i)
        #pragma unroll
        for (int j = 0; j < 2; ++j)
          acc[i][j] = MFMA16(af[i], bfr[j], acc[i][j]);
    }
    __syncthreads();
  }

  #pragma unroll
  for (int i = 0; i < 4; ++i) {
    const int rbase = m0 + wr*64 + i*16 + lhi*4;
    #pragma unroll
    for (int j = 0; j < 2; ++j) {
      const int col = n0 + wc*32 + j*16 + lrow;
      #pragma unroll
      for (int rr = 0; rr < 4; ++rr) {
        const size_t idx = (size_t)(rbase + rr) * 512 + col;
        const float old = accum ? bf2f(Pz[idx]) : 0.f;
        Pz[idx] = f2bf(old + acc[i][j][rr]);
      }
    }
  }
}

// -------- fallback combine ---------------------------------------------------
__global__ __launch_bounds__(256) void combineB_k(
    float* __restrict__ out, const u16* __restrict__ P,
    const float* __restrict__ rout, const float* __restrict__ b2)
{
  const int row = blockIdx.x, t = threadIdx.x;
  float r[8];
  #pragma unroll
  for (int e = 0; e < 8; ++e) r[e] = rout[(size_t)row*8 + e];
  #pragma unroll
  for (int cc = 0; cc < 2; ++cc) {
    const int c = t + cc*256;
    const size_t idx = (size_t)row*512 + c;
    float v = out[idx] + bf2f(P[idx]) + bf2f(P[(size_t)4096*512 + idx]);
    #pragma unroll
    for (int e = 0; e < 8; ++e) v += r[e] * b2[(size_t)e*512 + c];
    out[idx] = v;
  }
}

// -------- flash attention: KVBLK=128, paired q-blocks {qp,15-qp}, 256 blk ----
__global__ __launch_bounds__(256) void attn_k(
    const u16* __restrict__ qkv, const u16* __restrict__ vt, u16* __restrict__ o)
{
  const int bid = blockIdx.x;
  const int xcd = bid & 7, rr_ = bid >> 3;
  const int bh = (rr_ >> 3) * 8 + xcd;
  const int qp = rr_ & 7;
  const int b = bh >> 3, h = bh & 7;
  const int t = threadIdx.x, l = t & 63, w = t >> 6;
  const int lrow = l & 15, lhi = l >> 4;

  __shared__ u16 Ksm[2][128*64];
  __shared__ u16 Vsm[2][64*128];
  __shared__ u16 Psm[4][16][136];

  const int trow = t >> 3;
  const int csw = ((t & 7) ^ (trow & 7)) * 8;
  const int vrow = t >> 4;
  const int vsw = ((t & 15) ^ (vrow & 7)) * 8;
  const u16* gk = qkv + (size_t)(b*1024 + trow) * 1536 + 512 + h*64 + csw;
  const u16* gv = vt + (size_t)bh*65536 + (size_t)vrow*1024 + vsw;
  const f32x4 z4 = {0.f,0.f,0.f,0.f};

#define ASTAGE(buf, s0) do { \
    _Pragma("unroll") \
    for (int i = 0; i < 4; ++i) \
      GLDS16(gk + (size_t)((s0) + i*32) * 1536, (char*)Ksm[buf] + i*4096 + t*16); \
    _Pragma("unroll") \
    for (int i = 0; i < 4; ++i) \
      GLDS16(gv + (s0) + (size_t)(i*16)*1024,   (char*)Vsm[buf] + i*4096 + t*16); \
  } while (0)

  for (int pass = 0; pass < 2; ++pass) {
    const int qb = pass ? (15 - qp) : qp;
    const int t0w = qb*64 + w*16;
    const u16* qrow = qkv + (size_t)(b*1024 + t0w + lrow) * 1536 + h*64 + lhi*8;
    s16x8 qf0 = *(const s16x8*)qrow;
    s16x8 qf1 = *(const s16x8*)(qrow + 32);

    float m[4], sl[4];
    f32x4 oacc[4];
    #pragma unroll
    for (int i = 0; i < 4; ++i) { m[i] = -1e30f; sl[i] = 0.f; oacc[i] = z4; }

    const int nt = (qb >> 1) + 1;
    ASTAGE(0, 0);
    for (int kv = 0; kv < nt; ++kv) {
      const int s0 = kv * 128;
      if (kv + 1 < nt) {
        ASTAGE((kv + 1) & 1, s0 + 128);
        asm volatile("s_waitcnt vmcnt(8)" ::: "memory");
      } else {
        asm volatile("s_waitcnt vmcnt(0)" ::: "memory");
      }
      __builtin_amdgcn_s_barrier();
      __builtin_amdgcn_sched_barrier(0);
      const u16* Ks = Ksm[kv & 1];
      const u16* Vs = Vsm[kv & 1];

      f32x4 sacc[8];
      #pragma unroll
      for (int n = 0; n < 8; ++n) sacc[n] = z4;
      #pragma unroll
      for (int n = 0; n < 8; ++n) {
        const int r = n*16 + lrow;
        s16x8 kf0 = *(const s16x8*)((const char*)Ks + r*128 + ((lhi*16) ^ ((r & 7) << 4)));
        s16x8 kf1 = *(const s16x8*)((const char*)Ks + r*128 + ((64 + lhi*16) ^ ((r & 7) << 4)));
        sacc[n] = MFMA16(qf0, kf0, sacc[n]);
        sacc[n] = MFMA16(qf1, kf1, sacc[n]);
      }
      if (s0 + 127 > t0w) {
        #pragma unroll
        for (int n = 0; n < 8; ++n)
          #pragma unroll
          for (int rr = 0; rr < 4; ++rr)
            if (s0 + n*16 + lrow > t0w + lhi*4 + rr) sacc[n][rr] = -1e30f;
      }
      float pm[4];
      #pragma unroll
      for (int rr = 0; rr < 4; ++rr) {
        float a = fmaxf(fmaxf(sacc[0][rr], sacc[1][rr]), fmaxf(sacc[2][rr], sacc[3][rr]));
        float bmx = fmaxf(fmaxf(sacc[4][rr], sacc[5][rr]), fmaxf(sacc[6][rr], sacc[7][rr]));
        pm[rr] = fmaxf(a, bmx);
      }
      #pragma unroll
      for (int rr = 0; rr < 4; ++rr) {
        pm[rr] = fmaxf(pm[rr], __shfl_xor(pm[rr], 1));
        pm[rr] = fmaxf(pm[rr], __shfl_xor(pm[rr], 2));
        pm[rr] = fmaxf(pm[rr], __shfl_xor(pm[rr], 4));
        pm[rr] = fmaxf(pm[rr], __shfl_xor(pm[rr], 8));
      }
      float p[8][4], ps[4], scv[4];
      #pragma unroll
      for (int rr = 0; rr < 4; ++rr) {
        const float mn = fmaxf(m[rr], pm[rr]);
        scv[rr] = __expf(m[rr] - mn);
        m[rr] = mn;
        ps[rr] = 0.f;
        #pragma unroll
        for (int n = 0; n < 8; ++n) {
          p[n][rr] = __expf(sacc[n][rr] - mn);
          ps[rr] += p[n][rr];
        }
      }
      #pragma unroll
      for (int rr = 0; rr < 4; ++rr) {
        ps[rr] += __shfl_xor(ps[rr], 1);
        ps[rr] += __shfl_xor(ps[rr], 2);
        ps[rr] += __shfl_xor(ps[rr], 4);
        ps[rr] += __shfl_xor(ps[rr], 8);
        sl[rr] = sl[rr] * scv[rr] + ps[rr];
      }
      #pragma unroll
      for (int ct = 0; ct < 4; ++ct) {
        f32x4 t4 = oacc[ct];
        #pragma unroll
        for (int rr = 0; rr < 4; ++rr) t4[rr] *= scv[rr];
        oacc[ct] = t4;
      }
      #pragma unroll
      for (int n = 0; n < 8; ++n)
        #pragma unroll
        for (int rr = 0; rr < 4; ++rr)
          Psm[w][lhi*4 + rr][n*16 + lrow] = f2bf(p[n][rr]);
      asm volatile("s_waitcnt lgkmcnt(0)" ::: "memory");
      __builtin_amdgcn_sched_barrier(0);
      s16x8 pa[4];
      #pragma unroll
      for (int s = 0; s < 4; ++s)
        pa[s] = *(const s16x8*)&Psm[w][lrow][s*32 + lhi*8];
      #pragma unroll
      for (int ct = 0; ct < 4; ++ct) {
        const int r = ct*16 + lrow;
        #pragma unroll
        for (int s = 0; s < 4; ++s) {
          s16x8 vb = *(const s16x8*)((const char*)Vs + r*256 + ((s*64 + lhi*16) ^ ((r & 7) << 4)));
          oacc[ct] = MFMA16(pa[s], vb, oacc[ct]);
        }
      }
      __builtin_amdgcn_s_barrier();
      __builtin_amdgcn_sched_barrier(0);
    }
    #pragma unroll
    for (int ct = 0; ct < 4; ++ct)
      #pragma unroll
      for (int rr = 0; rr < 4; ++rr) {
        const int row = b*1024 + t0w + lhi*4 + rr;
        o[(size_t)row*512 + h*64 + ct*16 + lrow] = f2bf(oacc[ct][rr] / sl[rr]);
      }
  }
#undef ASTAGE
}

// -------- fused LN2 + router (fp32 exact top-2) + h2 bf16 output -------------
__global__ __launch_bounds__(256) void router_k(
    const float* __restrict__ x2, const float* __restrict__ g,
    const float* __restrict__ b, const float* __restrict__ Wr,
    const float* __restrict__ br, float* __restrict__ rt,
    u16* __restrict__ h2o)
{
  const int l = threadIdx.x & 63, w = threadIdx.x >> 6;
  const int tkn = blockIdx.x * 4 + w;
  const float* xr = x2 + (size_t)tkn * 512;
  float v[8];
  float s = 0.f, ss = 0.f;
  #pragma unroll
  for (int i = 0; i < 8; ++i) {
    v[i] = xr[l*8 + i];
    s += v[i]; ss += v[i]*v[i];
  }
  #pragma unroll
  for (int off = 1; off < 64; off <<= 1) {
    s  += __shfl_xor(s, off);
    ss += __shfl_xor(ss, off);
  }
  const float mu = s * (1.f/512.f);
  const float var = ss * (1.f/512.f) - mu*mu;
  const float rstd = rsqrtf(var + 1e-5f);
  float acc[8];
  #pragma unroll
  for (int e = 0; e < 8; ++e) acc[e] = 0.f;
  s16x8 hw;
  #pragma unroll
  for (int i = 0; i < 8; ++i) {
    const int c = l*8 + i;
    const float hv = (v[i] - mu) * rstd * g[c] + b[c];
    hw[i] = (short)f2bf(hv);
    const float* wrow = Wr + (size_t)c * 8;
    #pragma unroll
    for (int e = 0; e < 8; ++e) acc[e] += hv * wrow[e];
  }
  *(s16x8*)(h2o + (size_t)tkn*512 + l*8) = hw;
  #pragma unroll
  for (int e = 0; e < 8; ++e) {
    #pragma unroll
    for (int off = 1; off < 64; off <<= 1) acc[e] += __shfl_xor(acc[e], off);
    acc[e] += br[e];
  }
  int e1 = 0;
  #pragma unroll
  for (int e = 1; e < 8; ++e) if (acc[e] > acc[e1]) e1 = e;
  int e2 = (e1 == 0) ? 1 : 0;
  #pragma unroll
  for (int e = 0; e < 8; ++e) if (e != e1 && acc[e] > acc[e2]) e2 = e;
  const float mx = fmaxf(acc[e1], 0.f);
  float Z = 0.f;
  #pragma unroll
  for (int e = 0; e < 8; ++e) {
    const float mv = (e == e1 || e == e2) ? acc[e] : 0.f;
    Z += __expf(mv - mx);
  }
  if (l < 8) {
    const float mv = (l == e1 || l == e2) ? acc[l] : 0.f;
    rt[(size_t)tkn * 8 + l] = __expf(mv - mx) / Z;
  }
}

extern "C" void kernel_launch(void* const* d_in, const int* in_sizes, int n_in,
                              void* d_out, int out_size, void* d_ws, size_t ws_size,
                              hipStream_t stream) {
  const float* x    = (const float*)d_in[0];
  const float* ln1g = (const float*)d_in[1];
  const float* ln1b = (const float*)d_in[2];
  const float* ln2g = (const float*)d_in[3];
  const float* ln2b = (const float*)d_in[4];
  const float* Wq   = (const float*)d_in[5];
  const float* Wk   = (const float*)d_in[6];
  const float* Wv   = (const float*)d_in[7];
  const float* Wp   = (const float*)d_in[8];
  const float* bp   = (const float*)d_in[9];
  const float* Wr   = (const float*)d_in[10];
  const float* br   = (const float*)d_in[11];
  const float* W1   = (const float*)d_in[12];
  const float* b1   = (const float*)d_in[13];
  const float* W2   = (const float*)d_in[14];
  const float* b2   = (const float*)d_in[15];
  float* out = (float*)d_out;

  const int pathH = (ws_size >= (size_t)138543104) ? 1 : 0;  // halves MoE
  const int pathN = (ws_size >= (size_t)104988672) ? 1 : 0;  // quarters MoE

  char* ws = (char*)d_ws;
  size_t off = 0;
  auto alloc = [&](size_t bytes) -> char* {
    char* p = ws + off;
    off += (bytes + 255) & ~(size_t)255;
    return p;
  };
  u16* w1_t = (u16*)alloc((size_t)8*2048*512*2);   // flat [16384][512]
  u16* w2f  = (u16*)alloc((size_t)8*512*2048*2);   // flat [512][16384] (pathN/H)
  u16* h2b  = (u16*)alloc((size_t)4096*512*2);
  float* rout = (float*)alloc((size_t)4096*8*4);
  u16* hidq = (u16*)alloc(pathH ? (size_t)2048*16384*2 : (size_t)4096*4096*2);
  u16* Ppl  = (u16*)alloc(pathH ? (size_t)16*2048*512*2
                                : (pathN ? (size_t)32*1024*512*2 : (size_t)2*4096*512*2));
  // attention-phase overlays inside hidq (>=32 MiB region, dead before MoE):
  u16* wqkv_t = (u16*)hidq;                          // 1.5 MiB
  u16* wp_t   = (u16*)((char*)hidq + 1572864);       // 0.5 MiB
  u16* hb     = (u16*)((char*)hidq + 2097152);       // 4 MiB
  u16* attnb  = (u16*)((char*)hidq + 6291456);       // 4 MiB
  u16* qkvb   = (u16*)((char*)hidq + 10485760);      // 12 MiB
  u16* vtb    = (u16*)((char*)hidq + 23068672);      // 8 MiB (ends 30 MiB)

  const dim3 tb(32, 8);
  transqkv_k<<<dim3(2,16,32), tb, 0, stream>>>(Wq, Wk, Wv, Wp, wqkv_t, wp_t);
  if (pathN) {
    transW_k<<<dim3(64,16,16), tb, 0, stream>>>(W1, W2, w1_t, w2f);
  } else {
    transpose_k<<<dim3(64,16,8), tb, 0, stream>>>(W1, w1_t, 512, 2048,
        (long long)512*2048, (long long)2048*512, 1.f);
    transpose_k<<<dim3(16,64,8), tb, 0, stream>>>(W2, w2f, 2048, 512,
        (long long)2048*512, (long long)512*2048, 1.f);
  }

  ln_k<<<4096, 256, 0, stream>>>(x, ln1g, ln1b, hb);
  gemm2p<96,0><<<dim3(32,16), 256, 0, stream>>>(hb, wqkv_t, 4096, 1536, 512, 512, 512,
                                                qkvb, nullptr, nullptr, nullptr, 0);
  vtrans_k<<<dim3(32,2,32), tb, 0, stream>>>(qkvb, vtb);
  attn_k<<<256, 256, 0, stream>>>(qkvb, vtb, attnb);
  gemm2p<64,2><<<dim3(32,8), 256, 0, stream>>>(attnb, wp_t, 4096, 512, 512, 512, 512,
                                               nullptr, out, bp, x, 0);
  router_k<<<1024, 256, 0, stream>>>(out, ln2g, ln2b, Wr, br, rout, h2b);

  if (pathH) {
    for (int h = 0; h < 2; ++h) {
      gemm8p<8,2><<<512, 512, 0, stream>>>(h2b + (size_t)h*2048*512, w1_t, 512, 512,
                                           hidq, b1, rout + (size_t)h*16384);
      gemm8p<16,5><<<256, 512, 0, stream>>>(hidq, w2f, 16384, 16384,
                                            Ppl, nullptr, nullptr);
      combineZ_k<16><<<2048, 256, 0, stream>>>(out + (size_t)h*2048*512, Ppl,
                                               (size_t)2048*512,
                                               rout + (size_t)h*16384, b2);
    }
  } else if (pathN) {
    for (int q = 0; q < 4; ++q) {
      gemm8p<8,1><<<256, 512, 0, stream>>>(h2b + (size_t)q*1024*512, w1_t, 512, 512,
                                           hidq, b1, rout + (size_t)q*8192);
      gemm8p<8,4><<<256, 512, 0, stream>>>(hidq, w2f, 16384, 16384,
                                           Ppl, nullptr, nullptr);
      combineZ_k<32><<<1024, 256, 0, stream>>>(out + (size_t)q*1024*512, Ppl,
                                               (size_t)1024*512,
                                               rout + (size_t)q*8192, b2);
    }
  } else {
    for (int p = 0; p < 4; ++p) {
      const int e0 = 2*p;
      gemm2p<128,1><<<dim3(32,32), 256, 0, stream>>>(h2b, w1_t + (size_t)e0*2048*512,
                                                     4096, 4096, 512, 512, 512,
                                                     hidq, nullptr, b1 + (size_t)e0*2048, rout, e0);
      gemm2_k<<<dim3(32,8,2), 256, 0, stream>>>(hidq, w2f, Ppl, e0, p > 0 ? 1 : 0);
    }
    combineB_k<<<4096, 256, 0, stream>>>(out, Ppl, rout, b2);
  }
}